// Round 4
// baseline (269.408 us; speedup 1.0000x reference)
//
#include <hip/hip_runtime.h>

typedef __attribute__((ext_vector_type(8))) short bf16x8;
typedef __attribute__((ext_vector_type(4))) float f32x4;

#define BB 1024
#define TT 256
#define DD 63
#define HH 128
#define CHUNK 4    // 4 batch rows/block, grid 256 = 1 block/CU
#define HSTR 160   // shorts; broadcast b128 reads exactly 2-way (free)
#define XSTR2 72   // shorts per xstage row: 2-way banks on GEMM B-frag reads
#define NSTR4 520  // floats per xpbuf row: <=2-way banks on C-init b128 reads
#define CT 4       // timesteps per xp chunk (M = 4b x 4t = 16, fully packed)

// Barrier that drains only LDS (lgkmcnt), NOT outstanding global loads.
#define LDS_BARRIER() asm volatile("s_waitcnt lgkmcnt(0)\n\ts_barrier" ::: "memory")

__device__ __forceinline__ short f2bf(float f) {
  unsigned u = __builtin_bit_cast(unsigned, f);
  u = (u + 0x7FFFu + ((u >> 16) & 1u)) >> 16;   // RNE
  return (short)u;
}
__device__ __forceinline__ float sigm(float x) {
  return __builtin_amdgcn_rcpf(1.f + __expf(-x));
}
__device__ __forceinline__ float tanh_fast(float x) {
  float e = __expf(2.f * x);
  return 1.f - 2.f * __builtin_amdgcn_rcpf(e + 1.f);
}

// R14 = R11 with the x-projection HOISTED out of the recurrence (chunked,
// in-LDS — the reference's own xp precompute, kept on-chip):
//  - every CT=4 steps, the next chunk's xp[4t][4b][512] is computed by 8
//    MFMAs/wave (M=16 fully packed: 4 batches x 4 timesteps), spread 2/step,
//    accumulated in regs, written fp32 (+bias folded) to LDS at chunk end;
//  - t-loop gate chain: 4 hh MFMAs with C-init = ds_read_b128 of xp
//    (replaces bias-init + 2 x-MFMAs + Bx reads + per-step x streaming);
//  - per-step MFMAs 192 -> 144 (floor 931 -> 698 cyc), dep chain 6 -> 4.
// xp stays fp32 (accumulation-order-only numerics delta; absmax has no
// headroom for a bf16 re-round). xp single-buffered: chunk's last step does
// read-Cinit -> barrier -> write-next-xp/stage-X -> barrier. X staged
// per-chunk (4 KB) by 252 threads, double-buffered, loads issued 2 chunks
// ahead (in flight across lgkm-only barriers).
// Kept: launch_bounds(512,2) (R4); grid=256 = 1 block/CU (R5); HSTR=160
// (R7); fused epilogue (R11: one-step bwd cell + full FC, fp32).
__global__ __launch_bounds__(512, 2)
void bilstm_fused_kernel(const float* __restrict__ X,
                         const float* __restrict__ Wih,
                         const float* __restrict__ Whh,
                         const float* __restrict__ bih,
                         const float* __restrict__ bhh,
                         const float* __restrict__ Wih_b,
                         const float* __restrict__ bih_b,
                         const float* __restrict__ bhh_b,
                         const float* __restrict__ Wfc,
                         const float* __restrict__ bfc,
                         float* __restrict__ out) {
  __shared__ __align__(16) short hbuf[2 * 4 * HSTR];       // h^T bf16, dbuf (2560 B)
  __shared__ __align__(16) float xpbuf[16 * NSTR4];        // xp fp32 [tl*4+b][512] (33280 B)
  __shared__ __align__(16) short xstage[2 * 16 * XSTR2];   // X bf16 [(tl*4+b)][64] dbuf (4608 B)
  __shared__ __align__(16) float fst[4 * 256];             // epilogue [h_f ; h_b]
  __shared__ __align__(16) float xl[4 * 64];               // x_last fp32
  __shared__ __align__(16) float glb[4 * 512];             // bwd gate pre-acts

  const int tid  = threadIdx.x;
  const int wave = tid >> 6;
  const int lane = tid & 63;
  const int quad = lane >> 4;
  const int l15  = lane & 15;
  const int b0   = blockIdx.x * CHUNK;
  const int br   = l15 & 3;        // this lane's batch row
  const int p    = l15 >> 2;       // duplicate-group index -> valid acc reg

  // ---- register-resident W fragments as MFMA A operands ----
  bf16x8 Ah[4][4];   // [gate][kstep], W_hh
  bf16x8 Axw[4][2];  // [gate][kstep], W_ih (K padded 63->64); used by xp-GEMM
  f32x4  bias[4];    // xp-GEMM C-init: col = wave*16 + quad*4 + q
#pragma unroll
  for (int g = 0; g < 4; ++g) {
    const int n = g * 128 + wave * 16 + l15;
    const float* wr = Whh + (size_t)n * HH;
#pragma unroll
    for (int ks = 0; ks < 4; ++ks) {
      const int k0 = ks * 32 + quad * 8;
      f32x4 w0 = *(const f32x4*)(wr + k0);
      f32x4 w1 = *(const f32x4*)(wr + k0 + 4);
      bf16x8 v;
#pragma unroll
      for (int jj = 0; jj < 4; ++jj) { v[jj] = f2bf(w0[jj]); v[4 + jj] = f2bf(w1[jj]); }
      Ah[g][ks] = v;
    }
    const float* xr = Wih + (size_t)n * DD;
#pragma unroll
    for (int ks = 0; ks < 2; ++ks) {
      const int k0 = ks * 32 + quad * 8;
      bf16x8 v;
#pragma unroll
      for (int jj = 0; jj < 8; ++jj) {
        const int k = k0 + jj;
        v[jj] = (k < DD) ? f2bf(xr[k]) : (short)0;
      }
      Axw[g][ks] = v;
    }
    const int cb = g * 128 + wave * 16 + quad * 4;
    f32x4 b1 = *(const f32x4*)&bih[cb];
    f32x4 b2 = *(const f32x4*)&bhh[cb];
    bias[g] = b1 + b2;
  }

  // zero h buffers (h(0)=0); zero xstage pad col k=63 (both buffers)
  for (int i = tid; i < 2 * 4 * HSTR; i += 512) hbuf[i] = 0;
  if (tid < 32) {
    const int bufc = tid >> 4, c = tid & 15;
    xstage[bufc * 16 * XSTR2 + c * XSTR2 + DD] = 0;
  }

  // ---- X chunk staging: 252 threads, 4 elems each (16 rows x 63 cols) ----
  // elem e = c*63 + k, c = tl*4 + b (tl = within-chunk t, b = batch row)
  const bool sthr = (tid < 252);
  int so_[4];              // xstage row-local offset c*XSTR2 + k
  const float* sx_[4];     // &X[b0+b][tl][k] (chunk 0 base)
#pragma unroll
  for (int j = 0; j < 4; ++j) {
    const int e = tid + 252 * j;
    const int c = e / DD, k = e - DD * c;
    so_[j] = c * XSTR2 + k;
    sx_[j] = X + ((size_t)(b0 + (c & 3)) * TT + (c >> 2)) * DD + k;
  }

  // prologue: stage chunk 0, GEMM chunk 0 -> xpbuf, stage chunk 1
  if (sthr) {
#pragma unroll
    for (int j = 0; j < 4; ++j) xstage[so_[j]] = f2bf(sx_[j][0]);
  }
  float xr1_[4];
  if (sthr) {
#pragma unroll
    for (int j = 0; j < 4; ++j) xr1_[j] = sx_[j][CT * DD];   // chunk 1
  }
  __syncthreads();
#pragma unroll
  for (int g = 0; g < 4; ++g) {
    bf16x8 B0 = *(const bf16x8*)&xstage[l15 * XSTR2 + quad * 8];
    bf16x8 B1 = *(const bf16x8*)&xstage[l15 * XSTR2 + 32 + quad * 8];
    f32x4 px = __builtin_amdgcn_mfma_f32_16x16x32_bf16(Axw[g][0], B0, bias[g], 0, 0, 0);
    px = __builtin_amdgcn_mfma_f32_16x16x32_bf16(Axw[g][1], B1, px, 0, 0, 0);
    *(f32x4*)&xpbuf[l15 * NSTR4 + g * 128 + wave * 16 + quad * 4] = px;
  }
  if (sthr) {
#pragma unroll
    for (int j = 0; j < 4; ++j) xstage[16 * XSTR2 + so_[j]] = f2bf(xr1_[j]);
  }
  __syncthreads();

  float cc = 0.f, hv = 0.f;   // ONE element per lane: (batch=br, col=wave*16+quad*4+p)
  const int hcol = wave * 16 + quad * 4 + p;
  const bool s0 = (l15 & 4) != 0;
  const bool s1 = (l15 & 8) != 0;

  for (int cu = 0; cu < TT / CT; ++cu) {
    const int t0 = cu * CT;
    float xr_[4];     // X for chunk cu+2, loaded at s=0, staged at s=3
    f32x4 pxp[4];     // xp accumulators for chunk cu+1 (chain g done in step g)
#pragma unroll
    for (int s = 0; s < CT; ++s) {
      const int t = t0 + s;
      const int hcur = (t & 1) * (4 * HSTR);

      // issue global X loads for chunk cu+2 early (fly across lgkm barriers)
      if (s == 0 && cu <= TT / CT - 3 && sthr) {
#pragma unroll
        for (int j = 0; j < 4; ++j) xr_[j] = sx_[j][(size_t)(t0 + 2 * CT) * DD];
      }

      // h B-fragments: row br -> 4-way same-address broadcast, 2-way banks
      bf16x8 Bh_[4];
#pragma unroll
      for (int ks = 0; ks < 4; ++ks)
        Bh_[ks] = *(const bf16x8*)&hbuf[hcur + br * HSTR + ks * 32 + quad * 8];

      // xp-GEMM chain s for chunk cu+1 (independent of recurrence)
      if (cu < TT / CT - 1) {
        const int xs = ((cu + 1) & 1) * (16 * XSTR2);
        bf16x8 B0 = *(const bf16x8*)&xstage[xs + l15 * XSTR2 + quad * 8];
        bf16x8 B1 = *(const bf16x8*)&xstage[xs + l15 * XSTR2 + 32 + quad * 8];
        f32x4 px = __builtin_amdgcn_mfma_f32_16x16x32_bf16(Axw[s][0], B0, bias[s], 0, 0, 0);
        pxp[s] = __builtin_amdgcn_mfma_f32_16x16x32_bf16(Axw[s][1], B1, px, 0, 0, 0);
      }

      // ---- hh chains: C-init = xp (bias folded), 4 dependent MFMAs ----
      float gact[4];
#pragma unroll
      for (int g = 0; g < 4; ++g) {
        f32x4 ci = *(const f32x4*)&xpbuf[(s * 4 + br) * NSTR4 + g * 128 + wave * 16 + quad * 4];
        f32x4 a = __builtin_amdgcn_mfma_f32_16x16x32_bf16(Ah[g][0], Bh_[0], ci, 0, 0, 0);
        a = __builtin_amdgcn_mfma_f32_16x16x32_bf16(Ah[g][1], Bh_[1], a, 0, 0, 0);
        a = __builtin_amdgcn_mfma_f32_16x16x32_bf16(Ah[g][2], Bh_[2], a, 0, 0, 0);
        a = __builtin_amdgcn_mfma_f32_16x16x32_bf16(Ah[g][3], Bh_[3], a, 0, 0, 0);
        const float a01 = s0 ? a[1] : a[0];
        const float a23 = s0 ? a[3] : a[2];
        const float v = s1 ? a23 : a01;
        gact[g] = (g == 2) ? tanh_fast(v) : sigm(v);
      }

      // ---- short exposed tail ----
      cc = gact[1] * cc + gact[0] * gact[2];
      hv = gact[3] * tanh_fast(cc);
      hbuf[(hcur ^ (4 * HSTR)) + br * HSTR + hcol] = f2bf(hv);

      if (s < CT - 1 || cu == TT / CT - 1) {
        LDS_BARRIER();   // h produced -> consumed next step
      } else {
        LDS_BARRIER();   // barrier A: all xp C-init reads of this chunk done
        // publish xp for chunk cu+1 (fp32)
#pragma unroll
        for (int g = 0; g < 4; ++g)
          *(f32x4*)&xpbuf[l15 * NSTR4 + g * 128 + wave * 16 + quad * 4] = pxp[g];
        // stage X for chunk cu+2 into xstage[(cu+2)&1] == xstage[cu&1]
        if (cu <= TT / CT - 3 && sthr) {
          const int xd2 = (cu & 1) * (16 * XSTR2);
#pragma unroll
          for (int j = 0; j < 4; ++j) xstage[xd2 + so_[j]] = f2bf(xr_[j]);
        }
        LDS_BARRIER();   // barrier B: xp/X visible for next chunk
      }
    }
  }

  // ==================== fused epilogue (R11, unchanged) ====================
  // stage h_f (fwd half) and x_last for the backward one-step cell
  fst[br * 256 + hcol] = hv;
  {
    const int xrow = tid / DD;
    const int xd   = tid - xrow * DD;
    if (tid < CHUNK * DD)
      xl[xrow * 64 + xd] = X[((size_t)(b0 + xrow) * TT + (TT - 1)) * DD + xd];
  }
  __syncthreads();

  // backward gate pre-activations, fp32: thread n covers gate-row n for all
  // 4 batches; x_last broadcast from LDS
  {
    const int n = tid;                       // 0..511
    const float* wr = Wih_b + (size_t)n * DD;
    const float bb2 = bih_b[n] + bhh_b[n];
    float a0 = bb2, a1 = bb2, a2 = bb2, a3 = bb2;
    for (int k = 0; k < DD; ++k) {
      const float w = wr[k];
      a0 += w * xl[0 * 64 + k];
      a1 += w * xl[1 * 64 + k];
      a2 += w * xl[2 * 64 + k];
      a3 += w * xl[3 * 64 + k];
    }
    glb[0 * 512 + n] = a0;
    glb[1 * 512 + n] = a1;
    glb[2 * 512 + n] = a2;
    glb[3 * 512 + n] = a3;
  }
  __syncthreads();

  // backward cell (f*c0 = 0): h_b = o * tanh(i*g)
  {
    const int b = tid >> 7, j = tid & 127;   // 4 b x 128 j = 512 threads
    const float iv = sigm(glb[b * 512 + j]);
    const float gv = tanh_fast(glb[b * 512 + 256 + j]);
    const float ov = sigm(glb[b * 512 + 384 + j]);
    fst[b * 256 + 128 + j] = ov * tanh_fast(iv * gv);
  }
  __syncthreads();

  // full FC (+ bias) on [h_f ; h_b]
  if (tid < CHUNK * 14) {
    const int rr = tid / 14, o = tid - rr * 14;
    const float* wr = Wfc + (size_t)o * (2 * HH);
    float acc = bfc[o];
#pragma unroll 16
    for (int k = 0; k < 2 * HH; ++k) acc += wr[k] * fst[rr * 256 + k];
    out[(size_t)(b0 + rr) * 14 + o] = acc;
  }
}

extern "C" void kernel_launch(void* const* d_in, const int* in_sizes, int n_in,
                              void* d_out, int out_size, void* d_ws, size_t ws_size,
                              hipStream_t stream) {
  const float* X     = (const float*)d_in[0];
  const float* Wih_f = (const float*)d_in[1];
  const float* Whh_f = (const float*)d_in[2];
  const float* bih_f = (const float*)d_in[3];
  const float* bhh_f = (const float*)d_in[4];
  const float* Wih_b = (const float*)d_in[5];
  // d_in[6] = W_hh_b: unused (backward dir needs only one step from zero state)
  const float* bih_b = (const float*)d_in[7];
  const float* bhh_b = (const float*)d_in[8];
  const float* Wfc   = (const float*)d_in[9];
  const float* bfc   = (const float*)d_in[10];
  float* out = (float*)d_out;

  bilstm_fused_kernel<<<BB / CHUNK, 512, 0, stream>>>(
      X, Wih_f, Whh_f, bih_f, bhh_f, Wih_b, bih_b, bhh_b, Wfc, bfc, out);
}

// Round 5
// 266.001 us; speedup vs baseline: 1.0128x; 1.0128x over previous
//
#include <hip/hip_runtime.h>

typedef __attribute__((ext_vector_type(8))) short bf16x8;
typedef __attribute__((ext_vector_type(4))) float f32x4;

#define BB 1024
#define TT 256
#define DD 63
#define HH 128
#define CHUNK 4    // 4 batch rows/block, grid 256 = 1 block/CU
#define HSTR 160   // shorts; 80 dwords ≡ 16 (mod 32): broadcast b128 reads exactly 2-way (free)
#define XSTR 96    // shorts; 48 dwords ≡ 16 (mod 32)

// Barrier that drains only LDS (lgkmcnt), NOT outstanding global loads.
#define LDS_BARRIER() asm volatile("s_waitcnt lgkmcnt(0)\n\ts_barrier" ::: "memory")

__device__ __forceinline__ short f2bf(float f) {
  unsigned u = __builtin_bit_cast(unsigned, f);
  u = (u + 0x7FFFu + ((u >> 16) & 1u)) >> 16;   // RNE
  return (short)u;
}
__device__ __forceinline__ float sigm(float x) {
  return __builtin_amdgcn_rcpf(1.f + __expf(-x));
}
__device__ __forceinline__ float tanh_fast(float x) {
  float e = __expf(2.f * x);
  return 1.f - 2.f * __builtin_amdgcn_rcpf(e + 1.f);
}

// R15 = R11 structure (207.5us, the best measured) + cross-step x-projection
// pipelined IN REGISTERS:
//   - during step t, 8 independent MFMAs compute xC[g] = bias + Wih·x(t+1)
//     into VGPRs, issued AFTER the gate activations so they fill the matrix
//     pipe during the cc/tanh/ds_write tail;
//   - step t's hh chain starts from C-init = xC[g] (computed last step):
//     dependent chain 6 -> 4 MFMAs before the activation select.
// R14 post-mortem: hoisting xp through LDS cut MfmaUtil 42.7->30.4 (exactly
// proportional to 192->144 MFMAs) but dur ROSE 207->217us with bank
// conflicts 1.34M->9.48M and 4.6MB scratch writes — MFMA issue is NOT the
// binding constraint; the serial step structure is. R15 keeps the chain
// shortening with ZERO new LDS traffic (Bx reads identical pattern, shifted
// one slot; MFMA count unchanged at 192/step).
// Numerics: accumulation order bias+x-then-hh (R14 made the same reorder,
// absmax identical 0.001953).
// Kept: launch_bounds(512,2) (R4); grid=256 = 1 block/CU (R5); HSTR=160/
// XSTR=96 (R7); one lgkm-only barrier/step (R8); per-gate stagger (R10);
// fused epilogue (R11).
__global__ __launch_bounds__(512, 2)
void bilstm_fused_kernel(const float* __restrict__ X,
                         const float* __restrict__ Wih,
                         const float* __restrict__ Whh,
                         const float* __restrict__ bih,
                         const float* __restrict__ bhh,
                         const float* __restrict__ Wih_b,
                         const float* __restrict__ bih_b,
                         const float* __restrict__ bhh_b,
                         const float* __restrict__ Wfc,
                         const float* __restrict__ bfc,
                         float* __restrict__ out) {
  __shared__ __align__(16) short hbuf[2 * 4 * HSTR];   // h^T (bf16), rows=batch 0..3, dbuf
  __shared__ __align__(16) short xbuf[2 * 4 * XSTR];   // x^T (bf16), rows=batch 0..3, 2 slots
  __shared__ __align__(16) float fst[4 * 256];         // epilogue [h_f ; h_b] per batch
  __shared__ __align__(16) float xl[4 * 64];           // x_last fp32, pad 64
  __shared__ __align__(16) float glb[4 * 512];         // bwd gate pre-acts [b][n]

  const int tid  = threadIdx.x;
  const int wave = tid >> 6;
  const int lane = tid & 63;
  const int quad = lane >> 4;
  const int l15  = lane & 15;
  const int b0   = blockIdx.x * CHUNK;
  const int br   = l15 & 3;        // this lane's batch row
  // duplicate-group index p = l15>>2 selects which acc register is valid

  // ---- register-resident W fragments as MFMA A operands ----
  bf16x8 Ah[4][4];   // [gate][kstep], W_hh
  bf16x8 Axw[4][2];  // [gate][kstep], W_ih (K padded 63->64)
  f32x4  bias[4];    // bias per acc reg q: col = wave*16 + quad*4 + q
#pragma unroll
  for (int g = 0; g < 4; ++g) {
    const int n = g * 128 + wave * 16 + l15;
    const float* wr = Whh + (size_t)n * HH;
#pragma unroll
    for (int ks = 0; ks < 4; ++ks) {
      const int k0 = ks * 32 + quad * 8;
      f32x4 w0 = *(const f32x4*)(wr + k0);
      f32x4 w1 = *(const f32x4*)(wr + k0 + 4);
      bf16x8 v;
#pragma unroll
      for (int jj = 0; jj < 4; ++jj) { v[jj] = f2bf(w0[jj]); v[4 + jj] = f2bf(w1[jj]); }
      Ah[g][ks] = v;
    }
    const float* xr = Wih + (size_t)n * DD;
#pragma unroll
    for (int ks = 0; ks < 2; ++ks) {
      const int k0 = ks * 32 + quad * 8;
      bf16x8 v;
#pragma unroll
      for (int jj = 0; jj < 8; ++jj) {
        const int k = k0 + jj;
        v[jj] = (k < DD) ? f2bf(xr[k]) : (short)0;
      }
      Axw[g][ks] = v;
    }
    const int cb = g * 128 + wave * 16 + quad * 4;
    f32x4 b1 = *(const f32x4*)&bih[cb];
    f32x4 b2 = *(const f32x4*)&bhh[cb];
    bias[g] = b1 + b2;
  }

  // zero h buffers (h(0)=0); x pad columns zeroed once (both slots)
  for (int i = tid; i < 2 * 4 * HSTR; i += 512) hbuf[i] = 0;
  if (tid >= CHUNK * DD && tid < 256) {
    const int rr = tid & 3;
    xbuf[rr * XSTR + DD] = 0;
    xbuf[4 * XSTR + rr * XSTR + DD] = 0;
  }

  // x staging: 4 rows x 63 cols = 252 threads. Pipeline runs one step
  // earlier than R11: prologue fills BOTH slots (x(0), x(1)); during step t
  // we write x(t+2) into slot[t&1] and hold x(t+3) in a register.
  const int xrow = tid / DD;
  const int xd   = tid - xrow * DD;
  const bool xthr = (tid < CHUNK * DD);
  const float* xptr = X + ((size_t)(b0 + xrow) * TT) * DD + xd;
  float xv_pend = 0.f;
  if (xthr) {
    xbuf[xrow * XSTR + xd] = f2bf(xptr[0]);                // slot 0 = x(0)
    xbuf[4 * XSTR + xrow * XSTR + xd] = f2bf(xptr[DD]);    // slot 1 = x(1)
    xv_pend = xptr[2 * DD];                                 // x(2)
    xptr += 3 * DD;
  }
  __syncthreads();

  // prologue xp: xC[g] = bias + Wih·x(0)  (C-init for step t=0's hh chain)
  f32x4 xC[4];
  {
    bf16x8 B0 = *(const bf16x8*)&xbuf[br * XSTR + quad * 8];
    bf16x8 B1 = *(const bf16x8*)&xbuf[br * XSTR + 32 + quad * 8];
#pragma unroll
    for (int g = 0; g < 4; ++g) {
      f32x4 px = __builtin_amdgcn_mfma_f32_16x16x32_bf16(Axw[g][0], B0, bias[g], 0, 0, 0);
      xC[g] = __builtin_amdgcn_mfma_f32_16x16x32_bf16(Axw[g][1], B1, px, 0, 0, 0);
    }
  }

  float cc = 0.f, hv = 0.f;   // ONE element per lane: (batch=br, col=wave*16+quad*4+p)
  const int hcol = wave * 16 + quad * 4 + (l15 >> 2);
  const bool s0 = (l15 & 4) != 0;
  const bool s1 = (l15 & 8) != 0;

  for (int t = 0; t < TT; ++t) {
    const int xcur = (t & 1) * (4 * XSTR);
    const int hcur = (t & 1) * (4 * HSTR);

    // issue x(t+3) early; stays in flight across the lgkm-only barrier
    float xv_new = 0.f;
    const bool pf3 = xthr && (t + 3 < TT);
    if (pf3) { xv_new = *xptr; xptr += DD; }

    // B-fragments: row br (l15&3) -> 4-way same-address broadcast, 2-way banks
    // Bh = h(t) from slot[t&1]; Bx = x(t+1) from slot[(t+1)&1] (stale-but-
    // valid old x at t=TT-1; resulting xC is never consumed).
    bf16x8 Bh_[4], Bx0, Bx1;
#pragma unroll
    for (int ks = 0; ks < 4; ++ks)
      Bh_[ks] = *(const bf16x8*)&hbuf[hcur + br * HSTR + ks * 32 + quad * 8];
    Bx0 = *(const bf16x8*)&xbuf[(xcur ^ (4 * XSTR)) + br * XSTR + quad * 8];
    Bx1 = *(const bf16x8*)&xbuf[(xcur ^ (4 * XSTR)) + br * XSTR + 32 + quad * 8];

    // ---- per-gate staggered: 4-MFMA dependent chain (C-init = xC from the
    //      previous step), then THAT gate's select+activation ----
    float gact[4];
#pragma unroll
    for (int g = 0; g < 4; ++g) {
      f32x4 a = __builtin_amdgcn_mfma_f32_16x16x32_bf16(Ah[g][0], Bh_[0], xC[g], 0, 0, 0);
      a = __builtin_amdgcn_mfma_f32_16x16x32_bf16(Ah[g][1], Bh_[1], a, 0, 0, 0);
      a = __builtin_amdgcn_mfma_f32_16x16x32_bf16(Ah[g][2], Bh_[2], a, 0, 0, 0);
      a = __builtin_amdgcn_mfma_f32_16x16x32_bf16(Ah[g][3], Bh_[3], a, 0, 0, 0);
      const float a01 = s0 ? a[1] : a[0];
      const float a23 = s0 ? a[3] : a[2];
      const float v = s1 ? a23 : a01;
      gact[g] = (g == 2) ? tanh_fast(v) : sigm(v);
    }

    // ---- next step's x-projection: 8 independent MFMAs, fill the matrix
    //      pipe during the VALU tail below ----
#pragma unroll
    for (int g = 0; g < 4; ++g) {
      f32x4 px = __builtin_amdgcn_mfma_f32_16x16x32_bf16(Axw[g][0], Bx0, bias[g], 0, 0, 0);
      xC[g] = __builtin_amdgcn_mfma_f32_16x16x32_bf16(Axw[g][1], Bx1, px, 0, 0, 0);
    }

    // ---- short exposed tail ----
    cc = gact[1] * cc + gact[0] * gact[2];
    hv = gact[3] * tanh_fast(cc);
    hbuf[(hcur ^ (4 * HSTR)) + br * HSTR + hcol] = f2bf(hv);

    // stage x(t+2) into slot[t&1] (consumed two steps later; nobody reads
    // slot[t&1] during step t, and the write lands before the barrier)
    if (xthr && (t + 2 < TT))
      xbuf[xcur + xrow * XSTR + xd] = f2bf(xv_pend);
    xv_pend = xv_new;
    LDS_BARRIER();   // the ONE barrier: h/x produced -> consumed next step
  }

  // ==================== fused epilogue ====================
  // stage h_f (fwd half) and x_last for the backward one-step cell
  fst[br * 256 + hcol] = hv;
  if (xthr)
    xl[xrow * 64 + xd] = X[((size_t)(b0 + xrow) * TT + (TT - 1)) * DD + xd];
  __syncthreads();

  // backward gate pre-activations, fp32 (identical math to old bwd kernel):
  // thread n covers gate-row n for all 4 batches; x_last broadcast from LDS
  {
    const int n = tid;                       // 0..511
    const float* wr = Wih_b + (size_t)n * DD;
    const float bb2 = bih_b[n] + bhh_b[n];
    float a0 = bb2, a1 = bb2, a2 = bb2, a3 = bb2;
    for (int k = 0; k < DD; ++k) {
      const float w = wr[k];
      a0 += w * xl[0 * 64 + k];
      a1 += w * xl[1 * 64 + k];
      a2 += w * xl[2 * 64 + k];
      a3 += w * xl[3 * 64 + k];
    }
    glb[0 * 512 + n] = a0;
    glb[1 * 512 + n] = a1;
    glb[2 * 512 + n] = a2;
    glb[3 * 512 + n] = a3;
  }
  __syncthreads();

  // backward cell (f*c0 = 0): h_b = o * tanh(i*g)
  {
    const int b = tid >> 7, j = tid & 127;   // 4 b x 128 j = 512 threads
    const float iv = sigm(glb[b * 512 + j]);
    const float gv = tanh_fast(glb[b * 512 + 256 + j]);
    const float ov = sigm(glb[b * 512 + 384 + j]);
    fst[b * 256 + 128 + j] = ov * tanh_fast(iv * gv);
  }
  __syncthreads();

  // full FC (+ bias) on [h_f ; h_b]
  if (tid < CHUNK * 14) {
    const int rr = tid / 14, o = tid - rr * 14;
    const float* wr = Wfc + (size_t)o * (2 * HH);
    float acc = bfc[o];
#pragma unroll 16
    for (int k = 0; k < 2 * HH; ++k) acc += wr[k] * fst[rr * 256 + k];
    out[(size_t)(b0 + rr) * 14 + o] = acc;
  }
}

extern "C" void kernel_launch(void* const* d_in, const int* in_sizes, int n_in,
                              void* d_out, int out_size, void* d_ws, size_t ws_size,
                              hipStream_t stream) {
  const float* X     = (const float*)d_in[0];
  const float* Wih_f = (const float*)d_in[1];
  const float* Whh_f = (const float*)d_in[2];
  const float* bih_f = (const float*)d_in[3];
  const float* bhh_f = (const float*)d_in[4];
  const float* Wih_b = (const float*)d_in[5];
  // d_in[6] = W_hh_b: unused (backward dir needs only one step from zero state)
  const float* bih_b = (const float*)d_in[7];
  const float* bhh_b = (const float*)d_in[8];
  const float* Wfc   = (const float*)d_in[9];
  const float* bfc   = (const float*)d_in[10];
  float* out = (float*)d_out;

  bilstm_fused_kernel<<<BB / CHUNK, 512, 0, stream>>>(
      X, Wih_f, Whh_f, bih_f, bhh_f, Wih_b, bih_b, bhh_b, Wfc, bfc, out);
}